// Round 2
// baseline (321.835 us; speedup 1.0000x reference)
//
#include <hip/hip_runtime.h>

#define Hh 32
#define Ss 2048
#define Ee 512
#define Dd 32
#define MNEG_INF -1.0e9f

typedef __attribute__((ext_vector_type(4))) float f32x4;
typedef __attribute__((ext_vector_type(8))) __bf16 bf16x8;
typedef __attribute__((ext_vector_type(8))) unsigned short ushort8;
typedef __attribute__((ext_vector_type(4))) unsigned short ushort4v;
typedef __attribute__((ext_vector_type(4))) unsigned int uint4v;

// float -> bf16 round-to-nearest-even, as raw ushort
__device__ inline unsigned short f2bf(float f) {
  union { float f; unsigned u; } x; x.f = f;
  unsigned r = x.u + 0x7fffu + ((x.u >> 16) & 1u);
  return (unsigned short)(r >> 16);
}

__device__ inline unsigned pk2(float a, float b) {
  return (unsigned)f2bf(a) | ((unsigned)f2bf(b) << 16);
}

// load 8 consecutive floats, convert to bf16x8 fragment
__device__ inline bf16x8 ld8bf(const float* p) {
  const float4* q = (const float4*)p;
  float4 u = q[0], v = q[1];
  bf16x8 r;
  r[0] = (__bf16)u.x; r[1] = (__bf16)u.y; r[2] = (__bf16)u.z; r[3] = (__bf16)u.w;
  r[4] = (__bf16)v.x; r[5] = (__bf16)v.y; r[6] = (__bf16)v.z; r[7] = (__bf16)v.w;
  return r;
}

// ---------------- Mask pack: int32 (0/1) [S][S] -> bitmask uint32 [S][S/32]
__global__ __launch_bounds__(256) void maskpack_kernel(
    const int* __restrict__ mask, unsigned int* __restrict__ bits) {
  int w = (int)blockIdx.x * 256 + (int)threadIdx.x;  // word index 0..S*S/32-1
  const int4* p = (const int4*)(mask + (size_t)w * 32);
  unsigned int b = 0;
  #pragma unroll
  for (int i = 0; i < 8; ++i) {
    int4 v = p[i];
    b |= (v.x ? 1u : 0u) << (4 * i + 0);
    b |= (v.y ? 1u : 0u) << (4 * i + 1);
    b |= (v.z ? 1u : 0u) << (4 * i + 2);
    b |= (v.w ? 1u : 0u) << (4 * i + 3);
  }
  bits[w] = b;
}

// ---------------- Phase 1: per-head projection  Out[s][d] = X[s][:] . W[d][:] + b[d]
// One wave computes a 16-row x 32-col output tile via mfma_f32_16x16x32_bf16.
// transposed==0: Out[h][s][d] row-major bf16.  transposed==1: Out[h][d][s] (for V).
__global__ __launch_bounds__(256) void proj_kernel(
    const float* __restrict__ X, const float* __restrict__ W,
    const float* __restrict__ bias, unsigned short* __restrict__ Out,
    int transposed) {
  int wid  = ((int)blockIdx.x * 256 + (int)threadIdx.x) >> 6;  // 0..4095
  int lane = (int)threadIdx.x & 63;
  int g = lane >> 4, li = lane & 15;
  int h = wid >> 7, rt = wid & 127;
  int row0 = rt << 4;

  const float* xr  = X + (size_t)h * Ss * Ee + (size_t)(row0 + li) * Ee + g * 8;
  const float* wlo = W + (size_t)li * Ee + g * 8;          // d = li
  const float* whi = W + (size_t)(li + 16) * Ee + g * 8;   // d = li+16

  f32x4 acc0 = {0.f, 0.f, 0.f, 0.f};
  f32x4 acc1 = {0.f, 0.f, 0.f, 0.f};
  #pragma unroll 4
  for (int e0 = 0; e0 < Ee; e0 += 32) {
    bf16x8 a  = ld8bf(xr + e0);    // A[m=row][k=e]
    bf16x8 b0 = ld8bf(wlo + e0);   // B[k=e][n=d]   = W[d][e]
    bf16x8 b1 = ld8bf(whi + e0);
    acc0 = __builtin_amdgcn_mfma_f32_16x16x32_bf16(a, b0, acc0, 0, 0, 0);
    acc1 = __builtin_amdgcn_mfma_f32_16x16x32_bf16(a, b1, acc1, 0, 0, 0);
  }
  float blo = bias[li], bhi = bias[li + 16];
  // D frag: row m = 4g+r (output row), col n = li (output d)
  if (!transposed) {
    unsigned short* ob = Out + (size_t)h * Ss * Dd + (size_t)(row0 + 4 * g) * Dd;
    #pragma unroll
    for (int r = 0; r < 4; ++r) {
      ob[r * Dd + li]      = f2bf(acc0[r] + blo);
      ob[r * Dd + li + 16] = f2bf(acc1[r] + bhi);
    }
  } else {
    unsigned short* ob = Out + (size_t)h * Dd * Ss;
    int s0 = row0 + 4 * g;
    #pragma unroll
    for (int r = 0; r < 4; ++r) {
      ob[(size_t)li * Ss + s0 + r]        = f2bf(acc0[r] + blo);
      ob[(size_t)(li + 16) * Ss + s0 + r] = f2bf(acc1[r] + bhi);
    }
  }
}

// ---------------- Phase 2: flash attention, one wave per (head, 16 q-rows)
// Swapped QK: S^T = mfma(K_tile, Q^T)  ->  lane holds 8 scores of ONE q-row
// (q = q0 + lane%16), keys {4g+r} and {16+4g+r}. Softmax row-reduce via
// shfl_xor(16/32). PV uses a bijective kk<->key permutation so the packed P
// values form the 16x16x32 A-frag directly (no shuffles): kk=8g+j <-> key =
// (j<4 ? 4g+j : 16+4g+j-4); V loaded with the same permutation from Vt[d][s].
__global__ __launch_bounds__(256) void attn_kernel(
    const unsigned short* __restrict__ Qb, const unsigned short* __restrict__ Kb,
    const unsigned short* __restrict__ Vt, const unsigned int* __restrict__ mbits,
    const float* __restrict__ inv_scale, float* __restrict__ out) {
  // XCD-chunked swizzle (1024 blocks % 8 == 0 -> bijective)
  int bid  = (int)blockIdx.x;
  int swz  = (bid & 7) * 128 + (bid >> 3);
  int wid  = swz * 4 + (((int)threadIdx.x) >> 6);  // 0..4095
  int lane = (int)threadIdx.x & 63;
  int g = lane >> 4, li = lane & 15;
  int h = wid >> 7, qt = wid & 127;
  int q0 = qt << 4;

  const unsigned short* kb  = Kb + (size_t)h * Ss * Dd;
  const unsigned short* vtb = Vt + (size_t)h * Dd * Ss;
  bf16x8 qf = __builtin_bit_cast(bf16x8,
      *(const ushort8*)(Qb + (size_t)h * Ss * Dd + (size_t)(q0 + li) * Dd + g * 8));
  float rscale = 1.0f / inv_scale[h];
  const unsigned int* mrow = mbits + (size_t)(q0 + li) * (Ss / 32);
  const unsigned short* vlo = vtb + (size_t)li * Ss + 4 * g;         // d = li
  const unsigned short* vhi = vtb + (size_t)(li + 16) * Ss + 4 * g;  // d = li+16

  f32x4 olo = {0.f, 0.f, 0.f, 0.f};
  f32x4 ohi = {0.f, 0.f, 0.f, 0.f};
  float M = -__builtin_inff(), L = 0.f;

  for (int kt = 0; kt < Ss; kt += 32) {
    // K fragments: A[m=key_local][k=d]
    bf16x8 k0 = __builtin_bit_cast(bf16x8,
        *(const ushort8*)(kb + (size_t)(kt + li) * Dd + g * 8));
    bf16x8 k1 = __builtin_bit_cast(bf16x8,
        *(const ushort8*)(kb + (size_t)(kt + 16 + li) * Dd + g * 8));
    f32x4 z = {0.f, 0.f, 0.f, 0.f};
    f32x4 st0 = __builtin_amdgcn_mfma_f32_16x16x32_bf16(k0, qf, z, 0, 0, 0);
    f32x4 st1 = __builtin_amdgcn_mfma_f32_16x16x32_bf16(k1, qf, z, 0, 0, 0);
    // st0[r] = S[q0+li][kt+4g+r], st1[r] = S[q0+li][kt+16+4g+r]

    unsigned int mw = mrow[kt >> 5];   // 32 mask bits for this q-row, keys kt..kt+31
    float s0[4], s1[4];
    #pragma unroll
    for (int r = 0; r < 4; ++r) {
      s0[r] = ((mw >> (4 * g + r)) & 1u)      ? MNEG_INF : st0[r] * rscale;
      s1[r] = ((mw >> (16 + 4 * g + r)) & 1u) ? MNEG_INF : st1[r] * rscale;
    }

    float mx = fmaxf(fmaxf(fmaxf(s0[0], s0[1]), fmaxf(s0[2], s0[3])),
                     fmaxf(fmaxf(s1[0], s1[1]), fmaxf(s1[2], s1[3])));
    mx = fmaxf(mx, __shfl_xor(mx, 16));
    mx = fmaxf(mx, __shfl_xor(mx, 32));
    float Mn = fmaxf(M, mx);
    float al = __expf(M - Mn);

    float p0[4], p1[4];
    #pragma unroll
    for (int r = 0; r < 4; ++r) { p0[r] = __expf(s0[r] - Mn); p1[r] = __expf(s1[r] - Mn); }
    float rs = ((p0[0] + p0[1]) + (p0[2] + p0[3])) + ((p1[0] + p1[1]) + (p1[2] + p1[3]));
    rs += __shfl_xor(rs, 16);
    rs += __shfl_xor(rs, 32);
    L = L * al + rs;
    M = Mn;

    // rescale O (rows are 4g+r -> fetch that row's alpha from lane 4g+r)
    #pragma unroll
    for (int r = 0; r < 4; ++r) {
      float ar = __shfl(al, 4 * g + r);
      olo[r] *= ar;
      ohi[r] *= ar;
    }

    // P -> bf16 A-frag (kk = 8g+j <-> key = j<4 ? 4g+j : 16+4g+(j-4))
    uint4v wv = { pk2(p0[0], p0[1]), pk2(p0[2], p0[3]),
                  pk2(p1[0], p1[1]), pk2(p1[2], p1[3]) };
    bf16x8 af = __builtin_bit_cast(bf16x8, wv);

    // V B-frags with identical kk permutation: Vt[d][kt+4g..+4] ++ Vt[d][kt+16+4g..+4]
    ushort4v va = *(const ushort4v*)(vlo + kt);
    ushort4v vb = *(const ushort4v*)(vlo + kt + 16);
    ushort4v vc = *(const ushort4v*)(vhi + kt);
    ushort4v vd = *(const ushort4v*)(vhi + kt + 16);
    ushort8 blo8 = { va[0], va[1], va[2], va[3], vb[0], vb[1], vb[2], vb[3] };
    ushort8 bhi8 = { vc[0], vc[1], vc[2], vc[3], vd[0], vd[1], vd[2], vd[3] };
    olo = __builtin_amdgcn_mfma_f32_16x16x32_bf16(
        af, __builtin_bit_cast(bf16x8, blo8), olo, 0, 0, 0);
    ohi = __builtin_amdgcn_mfma_f32_16x16x32_bf16(
        af, __builtin_bit_cast(bf16x8, bhi8), ohi, 0, 0, 0);
  }

  float* ob = out + (size_t)h * Ss * Dd + (size_t)(q0 + 4 * g) * Dd;
  #pragma unroll
  for (int r = 0; r < 4; ++r) {
    float Lr  = __shfl(L, 4 * g + r);
    float inv = 1.0f / Lr;
    ob[r * Dd + li]      = olo[r] * inv;
    ob[r * Dd + li + 16] = ohi[r] * inv;
  }
}

extern "C" void kernel_launch(void* const* d_in, const int* in_sizes, int n_in,
                              void* d_out, int out_size, void* d_ws, size_t ws_size,
                              hipStream_t stream) {
  const float* query = (const float*)d_in[0];
  const float* key   = (const float*)d_in[1];
  const float* value = (const float*)d_in[2];
  const int*   mask  = (const int*)d_in[3];      // bool -> int32 per harness contract
  const float* Wq = (const float*)d_in[4];
  const float* bq = (const float*)d_in[5];
  const float* Wk = (const float*)d_in[6];
  const float* bk = (const float*)d_in[7];
  const float* Wv = (const float*)d_in[8];
  const float* bv = (const float*)d_in[9];
  const float* inv_scale = (const float*)d_in[10];

  unsigned short* Qb   = (unsigned short*)d_ws;
  unsigned short* Kbuf = Qb + (size_t)Hh * Ss * Dd;
  unsigned short* Vtb  = Kbuf + (size_t)Hh * Ss * Dd;
  unsigned int*   bits = (unsigned int*)(Vtb + (size_t)Hh * Dd * Ss);
  float* out = (float*)d_out;

  dim3 blk(256);
  maskpack_kernel<<<(Ss * Ss / 32) / 256, blk, 0, stream>>>(mask, bits);
  proj_kernel<<<1024, blk, 0, stream>>>(query, Wq, bq, Qb, 0);
  proj_kernel<<<1024, blk, 0, stream>>>(key,   Wk, bk, Kbuf, 0);
  proj_kernel<<<1024, blk, 0, stream>>>(value, Wv, bv, Vtb, 1);
  attn_kernel<<<1024, blk, 0, stream>>>(Qb, Kbuf, Vtb, bits, inv_scale, out);
}

// Round 3
// 266.272 us; speedup vs baseline: 1.2087x; 1.2087x over previous
//
#include <hip/hip_runtime.h>

#define Hh 32
#define Ss 2048
#define Ee 512
#define Dd 32
#define MNEG -1.0e9f
#define LOG2E 1.4426950408889634f

typedef __attribute__((ext_vector_type(4))) float f32x4;
typedef __attribute__((ext_vector_type(8))) __bf16 bf16x8;
typedef __attribute__((ext_vector_type(8))) unsigned short ushort8;
typedef __attribute__((ext_vector_type(4))) unsigned short ushort4v;

// float -> bf16 round-to-nearest-even, as raw ushort (prep/proj epilogue only)
__device__ inline unsigned short f2bf(float f) {
  union { float f; unsigned u; } x; x.f = f;
  unsigned r = x.u + 0x7fffu + ((x.u >> 16) & 1u);
  return (unsigned short)(r >> 16);
}

// load 8 consecutive floats, convert to bf16x8 fragment
__device__ inline bf16x8 ld8bf(const float* p) {
  const float4* q = (const float4*)p;
  float4 u = q[0], v = q[1];
  bf16x8 r;
  r[0] = (__bf16)u.x; r[1] = (__bf16)u.y; r[2] = (__bf16)u.z; r[3] = (__bf16)u.w;
  r[4] = (__bf16)v.x; r[5] = (__bf16)v.y; r[6] = (__bf16)v.z; r[7] = (__bf16)v.w;
  return r;
}

// ---------------- Prep: pack mask int32 -> bits, convert Wq|Wk|Wv -> bf16
__global__ __launch_bounds__(256) void prep_kernel(
    const int* __restrict__ mask, unsigned int* __restrict__ bits,
    const float* __restrict__ Wq, const float* __restrict__ Wk,
    const float* __restrict__ Wv, unsigned short* __restrict__ Wb) {
  int b = (int)blockIdx.x, t = (int)threadIdx.x;
  if (b < 512) {
    int w = b * 256 + t;  // word index 0..S*S/32-1
    const int4* p = (const int4*)(mask + (size_t)w * 32);
    unsigned int bs = 0;
    #pragma unroll
    for (int i = 0; i < 8; ++i) {
      int4 v = p[i];
      bs |= (v.x ? 1u : 0u) << (4 * i + 0);
      bs |= (v.y ? 1u : 0u) << (4 * i + 1);
      bs |= (v.z ? 1u : 0u) << (4 * i + 2);
      bs |= (v.w ? 1u : 0u) << (4 * i + 3);
    }
    bits[w] = bs;
  } else {
    int i = (b - 512) * 1024 + t * 4;  // 48 blocks cover 3*32*512 = 49152 elems
    const float* src = (i < 16384) ? (Wq + i)
                     : (i < 32768) ? (Wk + (i - 16384)) : (Wv + (i - 32768));
    float4 v = *(const float4*)src;
    ushort4v o = { f2bf(v.x), f2bf(v.y), f2bf(v.z), f2bf(v.w) };
    *(ushort4v*)(Wb + i) = o;
  }
}

// ---------------- Merged projections: seg 0=Q (prescaled by log2e/inv_scale),
// 1=K (row-major), 2=V (transposed Vt[h][d][s]).  One wave = 16x32 out tile.
__global__ __launch_bounds__(256) void proj_kernel(
    const float* __restrict__ Xq, const float* __restrict__ Xk,
    const float* __restrict__ Xv, const unsigned short* __restrict__ Wb,
    const float* __restrict__ bq, const float* __restrict__ bk,
    const float* __restrict__ bv, const float* __restrict__ inv_scale,
    unsigned short* __restrict__ Qb, unsigned short* __restrict__ Kb,
    unsigned short* __restrict__ Vtb) {
  int blk  = (int)blockIdx.x;
  int seg  = blk >> 10;
  int wid  = ((blk & 1023) * 256 + (int)threadIdx.x) >> 6;  // 0..4095
  int lane = (int)threadIdx.x & 63;
  int g = lane >> 4, li = lane & 15;
  int h = wid >> 7, rt = wid & 127;
  int row0 = rt << 4;

  const float* X = (seg == 0) ? Xq : (seg == 1) ? Xk : Xv;
  const float* bias = (seg == 0) ? bq : (seg == 1) ? bk : bv;
  const unsigned short* W = Wb + seg * (Dd * Ee);

  const float* xr = X + (size_t)h * Ss * Ee + (size_t)(row0 + li) * Ee + g * 8;
  const unsigned short* wlo = W + (size_t)li * Ee + g * 8;         // d = li
  const unsigned short* whi = W + (size_t)(li + 16) * Ee + g * 8;  // d = li+16

  f32x4 acc0 = {0.f, 0.f, 0.f, 0.f};
  f32x4 acc1 = {0.f, 0.f, 0.f, 0.f};
  #pragma unroll 4
  for (int e0 = 0; e0 < Ee; e0 += 32) {
    bf16x8 a  = ld8bf(xr + e0);
    bf16x8 b0 = __builtin_bit_cast(bf16x8, *(const ushort8*)(wlo + e0));
    bf16x8 b1 = __builtin_bit_cast(bf16x8, *(const ushort8*)(whi + e0));
    acc0 = __builtin_amdgcn_mfma_f32_16x16x32_bf16(a, b0, acc0, 0, 0, 0);
    acc1 = __builtin_amdgcn_mfma_f32_16x16x32_bf16(a, b1, acc1, 0, 0, 0);
  }
  float blo = bias[li], bhi = bias[li + 16];
  float c = (seg == 0) ? (LOG2E / inv_scale[h]) : 1.0f;
  if (seg < 2) {
    unsigned short* ob = ((seg == 0) ? Qb : Kb) +
        (size_t)h * Ss * Dd + (size_t)(row0 + 4 * g) * Dd;
    #pragma unroll
    for (int r = 0; r < 4; ++r) {
      ob[r * Dd + li]      = f2bf((acc0[r] + blo) * c);
      ob[r * Dd + li + 16] = f2bf((acc1[r] + bhi) * c);
    }
  } else {
    unsigned short* ob = Vtb + (size_t)h * Dd * Ss;
    int s0 = row0 + 4 * g;
    #pragma unroll
    for (int r = 0; r < 4; ++r) {
      ob[(size_t)li * Ss + s0 + r]        = f2bf(acc0[r] + blo);
      ob[(size_t)(li + 16) * Ss + s0 + r] = f2bf(acc1[r] + bhi);
    }
  }
}

// ---------------- Flash attention, one wave per (head, 16 q-rows), KVBLK=64.
// Q pre-scaled by log2e/inv_scale -> softmax in exp2 domain.
// Swapped QK: lane holds scores of ONE q-row (q=q0+li), keys {4g+r}+16k offsets.
// Defer-max: common path has ZERO cross-lane ops (per-lane partial L, __all check).
__global__ __launch_bounds__(256) void attn_kernel(
    const unsigned short* __restrict__ Qb, const unsigned short* __restrict__ Kb,
    const unsigned short* __restrict__ Vt, const unsigned int* __restrict__ mbits,
    float* __restrict__ out) {
  int bid  = (int)blockIdx.x;
  int swz  = (bid & 7) * 128 + (bid >> 3);   // XCD-chunked, bijective (1024%8==0)
  int wid  = swz * 4 + (((int)threadIdx.x) >> 6);
  int lane = (int)threadIdx.x & 63;
  int g = lane >> 4, li = lane & 15;
  int h = wid >> 7, qt = wid & 127;
  int q0 = qt << 4;

  const unsigned short* kb  = Kb + (size_t)h * Ss * Dd;
  const unsigned short* vtb = Vt + (size_t)h * Dd * Ss;
  bf16x8 qf = __builtin_bit_cast(bf16x8,
      *(const ushort8*)(Qb + (size_t)h * Ss * Dd + (size_t)(q0 + li) * Dd + g * 8));
  const unsigned int* mrow = mbits + (size_t)(q0 + li) * (Ss / 32);
  const unsigned short* vlo = vtb + (size_t)li * Ss + 4 * g;         // d = li
  const unsigned short* vhi = vtb + (size_t)(li + 16) * Ss + 4 * g;  // d = li+16

  f32x4 olo = {0.f, 0.f, 0.f, 0.f};
  f32x4 ohi = {0.f, 0.f, 0.f, 0.f};
  float M = -__builtin_inff(), Lp = 0.f;

  for (int kt = 0; kt < Ss; kt += 64) {
    // K fragments (4 independent QK MFMAs worth)
    bf16x8 k0 = __builtin_bit_cast(bf16x8, *(const ushort8*)(kb + (size_t)(kt      + li) * Dd + g * 8));
    bf16x8 k1 = __builtin_bit_cast(bf16x8, *(const ushort8*)(kb + (size_t)(kt + 16 + li) * Dd + g * 8));
    bf16x8 k2 = __builtin_bit_cast(bf16x8, *(const ushort8*)(kb + (size_t)(kt + 32 + li) * Dd + g * 8));
    bf16x8 k3 = __builtin_bit_cast(bf16x8, *(const ushort8*)(kb + (size_t)(kt + 48 + li) * Dd + g * 8));
    // V fragments early (hide L2 latency under QK)
    ushort4v va0 = *(const ushort4v*)(vlo + kt);
    ushort4v vb0 = *(const ushort4v*)(vlo + kt + 16);
    ushort4v va1 = *(const ushort4v*)(vlo + kt + 32);
    ushort4v vb1 = *(const ushort4v*)(vlo + kt + 48);
    ushort4v vc0 = *(const ushort4v*)(vhi + kt);
    ushort4v vd0 = *(const ushort4v*)(vhi + kt + 16);
    ushort4v vc1 = *(const ushort4v*)(vhi + kt + 32);
    ushort4v vd1 = *(const ushort4v*)(vhi + kt + 48);
    unsigned int w0 = mrow[kt >> 5];
    unsigned int w1 = mrow[(kt >> 5) + 1];

    f32x4 z = {0.f, 0.f, 0.f, 0.f};
    f32x4 st0 = __builtin_amdgcn_mfma_f32_16x16x32_bf16(k0, qf, z, 0, 0, 0);
    f32x4 st1 = __builtin_amdgcn_mfma_f32_16x16x32_bf16(k1, qf, z, 0, 0, 0);
    f32x4 st2 = __builtin_amdgcn_mfma_f32_16x16x32_bf16(k2, qf, z, 0, 0, 0);
    f32x4 st3 = __builtin_amdgcn_mfma_f32_16x16x32_bf16(k3, qf, z, 0, 0, 0);

    float s[16];
    #pragma unroll
    for (int r = 0; r < 4; ++r) {
      s[r]      = ((w0 >> (4 * g + r)) & 1u)      ? MNEG : st0[r];
      s[4 + r]  = ((w0 >> (16 + 4 * g + r)) & 1u) ? MNEG : st1[r];
      s[8 + r]  = ((w1 >> (4 * g + r)) & 1u)      ? MNEG : st2[r];
      s[12 + r] = ((w1 >> (16 + 4 * g + r)) & 1u) ? MNEG : st3[r];
    }

    // per-lane max (max3-friendly tree), no cross-lane in common path
    float m0 = fmaxf(fmaxf(s[0], s[1]), s[2]);
    float m1 = fmaxf(fmaxf(s[3], s[4]), s[5]);
    float m2 = fmaxf(fmaxf(s[6], s[7]), s[8]);
    float m3 = fmaxf(fmaxf(s[9], s[10]), s[11]);
    float m4 = fmaxf(fmaxf(s[12], s[13]), s[14]);
    float pmax = fmaxf(fmaxf(fmaxf(m0, m1), fmaxf(m2, m3)), fmaxf(m4, s[15]));

    if (!__all(pmax <= M + 8.0f)) {  // rare: max grew -> full reduce + rescale
      float rmax = fmaxf(pmax, __shfl_xor(pmax, 16));
      rmax = fmaxf(rmax, __shfl_xor(rmax, 32));
      float Mn = fmaxf(M, rmax);
      float al = __builtin_amdgcn_exp2f(M - Mn);  // M=-inf first iter -> 0
      M = Mn;
      Lp *= al;
      #pragma unroll
      for (int r = 0; r < 4; ++r) {
        float ar = __shfl(al, 4 * g + r);
        olo[r] *= ar;
        ohi[r] *= ar;
      }
    }

    float p[16];
    #pragma unroll
    for (int j = 0; j < 16; ++j) p[j] = __builtin_amdgcn_exp2f(s[j] - M);
    float rs = (((p[0] + p[1]) + (p[2] + p[3])) + ((p[4] + p[5]) + (p[6] + p[7]))) +
               (((p[8] + p[9]) + (p[10] + p[11])) + ((p[12] + p[13]) + (p[14] + p[15])));
    Lp += rs;

    // P -> bf16 A-frags via compiler cvt_pk (kk = 8g+j <-> key = j<4?4g+j:16+4g+j-4)
    bf16x8 af0, af1;
    #pragma unroll
    for (int j = 0; j < 8; ++j) { af0[j] = (__bf16)p[j]; af1[j] = (__bf16)p[8 + j]; }

    ushort8 blo0 = { va0[0], va0[1], va0[2], va0[3], vb0[0], vb0[1], vb0[2], vb0[3] };
    ushort8 bhi0 = { vc0[0], vc0[1], vc0[2], vc0[3], vd0[0], vd0[1], vd0[2], vd0[3] };
    ushort8 blo1 = { va1[0], va1[1], va1[2], va1[3], vb1[0], vb1[1], vb1[2], vb1[3] };
    ushort8 bhi1 = { vc1[0], vc1[1], vc1[2], vc1[3], vd1[0], vd1[1], vd1[2], vd1[3] };
    olo = __builtin_amdgcn_mfma_f32_16x16x32_bf16(af0, __builtin_bit_cast(bf16x8, blo0), olo, 0, 0, 0);
    ohi = __builtin_amdgcn_mfma_f32_16x16x32_bf16(af0, __builtin_bit_cast(bf16x8, bhi0), ohi, 0, 0, 0);
    olo = __builtin_amdgcn_mfma_f32_16x16x32_bf16(af1, __builtin_bit_cast(bf16x8, blo1), olo, 0, 0, 0);
    ohi = __builtin_amdgcn_mfma_f32_16x16x32_bf16(af1, __builtin_bit_cast(bf16x8, bhi1), ohi, 0, 0, 0);
  }

  // one-time cross-lane L reduce (row li), then per-output-row broadcast
  Lp += __shfl_xor(Lp, 16);
  Lp += __shfl_xor(Lp, 32);
  float* ob = out + (size_t)h * Ss * Dd + (size_t)(q0 + 4 * g) * Dd;
  #pragma unroll
  for (int r = 0; r < 4; ++r) {
    float Lr  = __shfl(Lp, 4 * g + r);
    float inv = 1.0f / Lr;
    ob[r * Dd + li]      = olo[r] * inv;
    ob[r * Dd + li + 16] = ohi[r] * inv;
  }
}

extern "C" void kernel_launch(void* const* d_in, const int* in_sizes, int n_in,
                              void* d_out, int out_size, void* d_ws, size_t ws_size,
                              hipStream_t stream) {
  const float* query = (const float*)d_in[0];
  const float* key   = (const float*)d_in[1];
  const float* value = (const float*)d_in[2];
  const int*   mask  = (const int*)d_in[3];
  const float* Wq = (const float*)d_in[4];
  const float* bq = (const float*)d_in[5];
  const float* Wk = (const float*)d_in[6];
  const float* bk = (const float*)d_in[7];
  const float* Wv = (const float*)d_in[8];
  const float* bv = (const float*)d_in[9];
  const float* inv_scale = (const float*)d_in[10];

  unsigned short* Qb   = (unsigned short*)d_ws;
  unsigned short* Kbuf = Qb + (size_t)Hh * Ss * Dd;
  unsigned short* Vtb  = Kbuf + (size_t)Hh * Ss * Dd;
  unsigned int*   bits = (unsigned int*)(Vtb + (size_t)Hh * Dd * Ss);
  unsigned short* Wb   = (unsigned short*)(bits + (size_t)Ss * Ss / 32);
  float* out = (float*)d_out;

  dim3 blk(256);
  prep_kernel<<<512 + 48, blk, 0, stream>>>(mask, bits, Wq, Wk, Wv, Wb);
  proj_kernel<<<3072, blk, 0, stream>>>(query, key, value, Wb, bq, bk, bv,
                                        inv_scale, Qb, Kbuf, Vtb);
  attn_kernel<<<1024, blk, 0, stream>>>(Qb, Kbuf, Vtb, bits, out);
}

// Round 4
// 211.969 us; speedup vs baseline: 1.5183x; 1.2562x over previous
//
#include <hip/hip_runtime.h>

#define Hh 32
#define Ss 2048
#define Ee 512
#define Dd 32
#define MNEG -1.0e9f
#define LOG2E 1.4426950408889634f
#define KV_SPLIT 4
#define KV_LEN (Ss / KV_SPLIT)   // 512 keys per wave

typedef __attribute__((ext_vector_type(4))) float f32x4;
typedef __attribute__((ext_vector_type(8))) __bf16 bf16x8;
typedef __attribute__((ext_vector_type(8))) unsigned short ushort8;
typedef __attribute__((ext_vector_type(4))) unsigned short ushort4v;

// float -> bf16 round-to-nearest-even, as raw ushort (prep/proj epilogue only)
__device__ inline unsigned short f2bf(float f) {
  union { float f; unsigned u; } x; x.f = f;
  unsigned r = x.u + 0x7fffu + ((x.u >> 16) & 1u);
  return (unsigned short)(r >> 16);
}

// load 8 consecutive floats, convert to bf16x8 fragment
__device__ inline bf16x8 ld8bf(const float* p) {
  const float4* q = (const float4*)p;
  float4 u = q[0], v = q[1];
  bf16x8 r;
  r[0] = (__bf16)u.x; r[1] = (__bf16)u.y; r[2] = (__bf16)u.z; r[3] = (__bf16)u.w;
  r[4] = (__bf16)v.x; r[5] = (__bf16)v.y; r[6] = (__bf16)v.z; r[7] = (__bf16)v.w;
  return r;
}

// ---------------- Prep: pack mask int32 -> bits, convert Wq|Wk|Wv -> bf16
__global__ __launch_bounds__(256) void prep_kernel(
    const int* __restrict__ mask, unsigned int* __restrict__ bits,
    const float* __restrict__ Wq, const float* __restrict__ Wk,
    const float* __restrict__ Wv, unsigned short* __restrict__ Wb) {
  int b = (int)blockIdx.x, t = (int)threadIdx.x;
  if (b < 512) {
    int w = b * 256 + t;  // word index 0..S*S/32-1
    const int4* p = (const int4*)(mask + (size_t)w * 32);
    unsigned int bs = 0;
    #pragma unroll
    for (int i = 0; i < 8; ++i) {
      int4 v = p[i];
      bs |= (v.x ? 1u : 0u) << (4 * i + 0);
      bs |= (v.y ? 1u : 0u) << (4 * i + 1);
      bs |= (v.z ? 1u : 0u) << (4 * i + 2);
      bs |= (v.w ? 1u : 0u) << (4 * i + 3);
    }
    bits[w] = bs;
  } else {
    int i = (b - 512) * 1024 + t * 4;  // 48 blocks cover 3*32*512 = 49152 elems
    const float* src = (i < 16384) ? (Wq + i)
                     : (i < 32768) ? (Wk + (i - 16384)) : (Wv + (i - 32768));
    float4 v = *(const float4*)src;
    ushort4v o = { f2bf(v.x), f2bf(v.y), f2bf(v.z), f2bf(v.w) };
    *(ushort4v*)(Wb + i) = o;
  }
}

// ---------------- Merged projections: seg 0=Q (prescaled by log2e/inv_scale),
// 1=K (row-major), 2=V (transposed + PV kk-permuted: within each 32-key tile,
// key j stored at pos(j) = j<16 ? 8*(j>>2)+(j&3) : 8*((j-16)>>2)+4+(j&3),
// so attn's PV B-fragment is one contiguous 16-B load at offset 8*g).
__global__ __launch_bounds__(256) void proj_kernel(
    const float* __restrict__ Xq, const float* __restrict__ Xk,
    const float* __restrict__ Xv, const unsigned short* __restrict__ Wb,
    const float* __restrict__ bq, const float* __restrict__ bk,
    const float* __restrict__ bv, const float* __restrict__ inv_scale,
    unsigned short* __restrict__ Qb, unsigned short* __restrict__ Kb,
    unsigned short* __restrict__ Vtb) {
  int blk  = (int)blockIdx.x;
  int seg  = blk >> 10;
  int wid  = ((blk & 1023) * 256 + (int)threadIdx.x) >> 6;  // 0..4095
  int lane = (int)threadIdx.x & 63;
  int g = lane >> 4, li = lane & 15;
  int h = wid >> 7, rt = wid & 127;
  int row0 = rt << 4;

  const float* X = (seg == 0) ? Xq : (seg == 1) ? Xk : Xv;
  const float* bias = (seg == 0) ? bq : (seg == 1) ? bk : bv;
  const unsigned short* W = Wb + seg * (Dd * Ee);

  const float* xr = X + (size_t)h * Ss * Ee + (size_t)(row0 + li) * Ee + g * 8;
  const unsigned short* wlo = W + (size_t)li * Ee + g * 8;         // d = li
  const unsigned short* whi = W + (size_t)(li + 16) * Ee + g * 8;  // d = li+16

  f32x4 acc0 = {0.f, 0.f, 0.f, 0.f};
  f32x4 acc1 = {0.f, 0.f, 0.f, 0.f};
  #pragma unroll 4
  for (int e0 = 0; e0 < Ee; e0 += 32) {
    bf16x8 a  = ld8bf(xr + e0);
    bf16x8 b0 = __builtin_bit_cast(bf16x8, *(const ushort8*)(wlo + e0));
    bf16x8 b1 = __builtin_bit_cast(bf16x8, *(const ushort8*)(whi + e0));
    acc0 = __builtin_amdgcn_mfma_f32_16x16x32_bf16(a, b0, acc0, 0, 0, 0);
    acc1 = __builtin_amdgcn_mfma_f32_16x16x32_bf16(a, b1, acc1, 0, 0, 0);
  }
  float blo = bias[li], bhi = bias[li + 16];
  float c = (seg == 0) ? (LOG2E / inv_scale[h]) : 1.0f;
  if (seg < 2) {
    unsigned short* ob = ((seg == 0) ? Qb : Kb) +
        (size_t)h * Ss * Dd + (size_t)(row0 + 4 * g) * Dd;
    #pragma unroll
    for (int r = 0; r < 4; ++r) {
      ob[r * Dd + li]      = f2bf((acc0[r] + blo) * c);
      ob[r * Dd + li + 16] = f2bf((acc1[r] + bhi) * c);
    }
  } else {
    unsigned short* ob = Vtb + (size_t)h * Dd * Ss;
    int s0 = row0 + 4 * g;
    int base = (s0 & ~31) + 8 * g + ((s0 & 16) ? 4 : 0);  // permuted position
    #pragma unroll
    for (int r = 0; r < 4; ++r) {
      ob[(size_t)li * Ss + base + r]        = f2bf(acc0[r] + blo);
      ob[(size_t)(li + 16) * Ss + base + r] = f2bf(acc1[r] + bhi);
    }
  }
}

// ---------------- Flash attention: one BLOCK per (head, 16 q-rows); its 4
// waves each handle 512 keys (split-KV), combined at the end through LDS.
// Q pre-scaled by log2e/inv_scale -> exp2-domain softmax. Swapped QK: lane
// holds scores of ONE q-row (q=q0+li). Defer-max: common path has zero
// cross-lane ops. PV B-frag = single 16-B load from permuted Vt.
__global__ __launch_bounds__(256) void attn_kernel(
    const unsigned short* __restrict__ Qb, const unsigned short* __restrict__ Kb,
    const unsigned short* __restrict__ Vt, const unsigned int* __restrict__ mbits,
    float* __restrict__ out) {
  __shared__ float sO[KV_SPLIT][8][64];
  __shared__ float sM[KV_SPLIT][16];
  __shared__ float sL[KV_SPLIT][16];

  int bid  = (int)blockIdx.x;
  int slot = (bid & 7) * 512 + (bid >> 3);   // XCD-chunked, bijective (4096%8==0)
  int w    = (int)threadIdx.x >> 6;          // kv-split index 0..3
  int lane = (int)threadIdx.x & 63;
  int g = lane >> 4, li = lane & 15;
  int h = slot >> 7, qt = slot & 127;
  int q0 = qt << 4;

  const unsigned short* kb  = Kb + (size_t)h * Ss * Dd;
  const unsigned short* vpb = Vt + (size_t)h * Dd * Ss;
  bf16x8 qf = __builtin_bit_cast(bf16x8,
      *(const ushort8*)(Qb + (size_t)h * Ss * Dd + (size_t)(q0 + li) * Dd + g * 8));
  const unsigned int* mrow = mbits + (size_t)(q0 + li) * (Ss / 32);
  const unsigned short* vlo = vpb + (size_t)li * Ss + 8 * g;         // d = li
  const unsigned short* vhi = vpb + (size_t)(li + 16) * Ss + 8 * g;  // d = li+16

  f32x4 olo = {0.f, 0.f, 0.f, 0.f};
  f32x4 ohi = {0.f, 0.f, 0.f, 0.f};
  float M = -__builtin_inff(), Lp = 0.f;

  int kbeg = w * KV_LEN, kend = kbeg + KV_LEN;
  for (int kt = kbeg; kt < kend; kt += 64) {
    bf16x8 k0 = __builtin_bit_cast(bf16x8, *(const ushort8*)(kb + (size_t)(kt      + li) * Dd + g * 8));
    bf16x8 k1 = __builtin_bit_cast(bf16x8, *(const ushort8*)(kb + (size_t)(kt + 16 + li) * Dd + g * 8));
    bf16x8 k2 = __builtin_bit_cast(bf16x8, *(const ushort8*)(kb + (size_t)(kt + 32 + li) * Dd + g * 8));
    bf16x8 k3 = __builtin_bit_cast(bf16x8, *(const ushort8*)(kb + (size_t)(kt + 48 + li) * Dd + g * 8));
    bf16x8 v0lo = __builtin_bit_cast(bf16x8, *(const ushort8*)(vlo + kt));
    bf16x8 v0hi = __builtin_bit_cast(bf16x8, *(const ushort8*)(vhi + kt));
    bf16x8 v1lo = __builtin_bit_cast(bf16x8, *(const ushort8*)(vlo + kt + 32));
    bf16x8 v1hi = __builtin_bit_cast(bf16x8, *(const ushort8*)(vhi + kt + 32));
    uint2 mw = *(const uint2*)(mrow + (kt >> 5));

    f32x4 z = {0.f, 0.f, 0.f, 0.f};
    f32x4 st0 = __builtin_amdgcn_mfma_f32_16x16x32_bf16(k0, qf, z, 0, 0, 0);
    f32x4 st1 = __builtin_amdgcn_mfma_f32_16x16x32_bf16(k1, qf, z, 0, 0, 0);
    f32x4 st2 = __builtin_amdgcn_mfma_f32_16x16x32_bf16(k2, qf, z, 0, 0, 0);
    f32x4 st3 = __builtin_amdgcn_mfma_f32_16x16x32_bf16(k3, qf, z, 0, 0, 0);

    // ---- half A: keys [kt, kt+32)
    {
      float s[8];
      #pragma unroll
      for (int r = 0; r < 4; ++r) {
        s[r]     = ((mw.x >> (4 * g + r)) & 1u)      ? MNEG : st0[r];
        s[4 + r] = ((mw.x >> (16 + 4 * g + r)) & 1u) ? MNEG : st1[r];
      }
      float pmax = fmaxf(fmaxf(fmaxf(s[0], s[1]), s[2]),
                         fmaxf(fmaxf(s[3], s[4]), fmaxf(fmaxf(s[5], s[6]), s[7])));
      if (!__all(pmax <= M + 8.0f)) {
        float rmax = fmaxf(pmax, __shfl_xor(pmax, 16));
        rmax = fmaxf(rmax, __shfl_xor(rmax, 32));
        float Mn = fmaxf(M, rmax);
        float al = __builtin_amdgcn_exp2f(M - Mn);
        M = Mn; Lp *= al;
        #pragma unroll
        for (int r = 0; r < 4; ++r) {
          float ar = __shfl(al, 4 * g + r);
          olo[r] *= ar; ohi[r] *= ar;
        }
      }
      float p[8];
      #pragma unroll
      for (int j = 0; j < 8; ++j) p[j] = __builtin_amdgcn_exp2f(s[j] - M);
      Lp += ((p[0] + p[1]) + (p[2] + p[3])) + ((p[4] + p[5]) + (p[6] + p[7]));
      bf16x8 af;
      #pragma unroll
      for (int j = 0; j < 8; ++j) af[j] = (__bf16)p[j];
      olo = __builtin_amdgcn_mfma_f32_16x16x32_bf16(af, v0lo, olo, 0, 0, 0);
      ohi = __builtin_amdgcn_mfma_f32_16x16x32_bf16(af, v0hi, ohi, 0, 0, 0);
    }
    // ---- half B: keys [kt+32, kt+64)
    {
      float s[8];
      #pragma unroll
      for (int r = 0; r < 4; ++r) {
        s[r]     = ((mw.y >> (4 * g + r)) & 1u)      ? MNEG : st2[r];
        s[4 + r] = ((mw.y >> (16 + 4 * g + r)) & 1u) ? MNEG : st3[r];
      }
      float pmax = fmaxf(fmaxf(fmaxf(s[0], s[1]), s[2]),
                         fmaxf(fmaxf(s[3], s[4]), fmaxf(fmaxf(s[5], s[6]), s[7])));
      if (!__all(pmax <= M + 8.0f)) {
        float rmax = fmaxf(pmax, __shfl_xor(pmax, 16));
        rmax = fmaxf(rmax, __shfl_xor(rmax, 32));
        float Mn = fmaxf(M, rmax);
        float al = __builtin_amdgcn_exp2f(M - Mn);
        M = Mn; Lp *= al;
        #pragma unroll
        for (int r = 0; r < 4; ++r) {
          float ar = __shfl(al, 4 * g + r);
          olo[r] *= ar; ohi[r] *= ar;
        }
      }
      float p[8];
      #pragma unroll
      for (int j = 0; j < 8; ++j) p[j] = __builtin_amdgcn_exp2f(s[j] - M);
      Lp += ((p[0] + p[1]) + (p[2] + p[3])) + ((p[4] + p[5]) + (p[6] + p[7]));
      bf16x8 af;
      #pragma unroll
      for (int j = 0; j < 8; ++j) af[j] = (__bf16)p[j];
      olo = __builtin_amdgcn_mfma_f32_16x16x32_bf16(af, v1lo, olo, 0, 0, 0);
      ohi = __builtin_amdgcn_mfma_f32_16x16x32_bf16(af, v1hi, ohi, 0, 0, 0);
    }
  }

  // per-row L (sum over the 4 g-replicas), M already row-uniform
  Lp += __shfl_xor(Lp, 16);
  Lp += __shfl_xor(Lp, 32);

  if (lane < 16) { sM[w][lane] = M; sL[w][lane] = Lp; }
  #pragma unroll
  for (int r = 0; r < 4; ++r) {
    sO[w][r][lane]     = olo[r];
    sO[w][4 + r][lane] = ohi[r];
  }
  __syncthreads();

  if (w == 0) {
    float* ob = out + (size_t)h * Ss * Dd + (size_t)q0 * Dd;
    #pragma unroll
    for (int r = 0; r < 4; ++r) {
      int row = 4 * g + r;
      float M0 = sM[0][row], M1 = sM[1][row], M2 = sM[2][row], M3 = sM[3][row];
      float Mg = fmaxf(fmaxf(M0, M1), fmaxf(M2, M3));
      float e0 = __builtin_amdgcn_exp2f(M0 - Mg);
      float e1 = __builtin_amdgcn_exp2f(M1 - Mg);
      float e2 = __builtin_amdgcn_exp2f(M2 - Mg);
      float e3 = __builtin_amdgcn_exp2f(M3 - Mg);
      float den = sL[0][row] * e0 + sL[1][row] * e1 + sL[2][row] * e2 + sL[3][row] * e3;
      float nlo = sO[0][r][lane] * e0 + sO[1][r][lane] * e1 +
                  sO[2][r][lane] * e2 + sO[3][r][lane] * e3;
      float nhi = sO[0][4 + r][lane] * e0 + sO[1][4 + r][lane] * e1 +
                  sO[2][4 + r][lane] * e2 + sO[3][4 + r][lane] * e3;
      float inv = 1.0f / den;
      ob[row * Dd + li]      = nlo * inv;
      ob[row * Dd + li + 16] = nhi * inv;
    }
  }
}

extern "C" void kernel_launch(void* const* d_in, const int* in_sizes, int n_in,
                              void* d_out, int out_size, void* d_ws, size_t ws_size,
                              hipStream_t stream) {
  const float* query = (const float*)d_in[0];
  const float* key   = (const float*)d_in[1];
  const float* value = (const float*)d_in[2];
  const int*   mask  = (const int*)d_in[3];
  const float* Wq = (const float*)d_in[4];
  const float* bq = (const float*)d_in[5];
  const float* Wk = (const float*)d_in[6];
  const float* bk = (const float*)d_in[7];
  const float* Wv = (const float*)d_in[8];
  const float* bv = (const float*)d_in[9];
  const float* inv_scale = (const float*)d_in[10];

  unsigned short* Qb   = (unsigned short*)d_ws;
  unsigned short* Kbuf = Qb + (size_t)Hh * Ss * Dd;
  unsigned short* Vtb  = Kbuf + (size_t)Hh * Ss * Dd;
  unsigned int*   bits = (unsigned int*)(Vtb + (size_t)Hh * Dd * Ss);
  unsigned short* Wb   = (unsigned short*)(bits + (size_t)Ss * Ss / 32);
  float* out = (float*)d_out;

  dim3 blk(256);
  prep_kernel<<<512 + 48, blk, 0, stream>>>(mask, bits, Wq, Wk, Wv, Wb);
  proj_kernel<<<3072, blk, 0, stream>>>(query, key, value, Wb, bq, bk, bv,
                                        inv_scale, Qb, Kbuf, Vtb);
  attn_kernel<<<4096, blk, 0, stream>>>(Qb, Kbuf, Vtb, bits, out);
}

// Round 6
// 200.114 us; speedup vs baseline: 1.6083x; 1.0592x over previous
//
#include <hip/hip_runtime.h>

#define Hh 32
#define Ss 2048
#define Ee 512
#define Dd 32
#define MNEG -1.0e9f
#define LOG2E 1.4426950408889634f
#define KV_SPLIT 4
#define KV_LEN (Ss / KV_SPLIT)   // 512 keys per wave

typedef __attribute__((ext_vector_type(4))) float f32x4;
typedef __attribute__((ext_vector_type(8))) __bf16 bf16x8;
typedef __attribute__((ext_vector_type(8))) unsigned short ushort8;
typedef __attribute__((ext_vector_type(4))) unsigned short ushort4v;

// float -> bf16 round-to-nearest-even, as raw ushort
__device__ inline unsigned short f2bf(float f) {
  union { float f; unsigned u; } x; x.f = f;
  unsigned r = x.u + 0x7fffu + ((x.u >> 16) & 1u);
  return (unsigned short)(r >> 16);
}

// ---------------- Prep: pack mask int32 -> bits, convert Wq|Wk|Wv -> bf16
__global__ __launch_bounds__(256) void prep_kernel(
    const int* __restrict__ mask, unsigned int* __restrict__ bits,
    const float* __restrict__ Wq, const float* __restrict__ Wk,
    const float* __restrict__ Wv, unsigned short* __restrict__ Wb) {
  int b = (int)blockIdx.x, t = (int)threadIdx.x;
  if (b < 512) {
    int w = b * 256 + t;  // word index 0..S*S/32-1
    const int4* p = (const int4*)(mask + (size_t)w * 32);
    unsigned int bs = 0;
    #pragma unroll
    for (int i = 0; i < 8; ++i) {
      int4 v = p[i];
      bs |= (v.x ? 1u : 0u) << (4 * i + 0);
      bs |= (v.y ? 1u : 0u) << (4 * i + 1);
      bs |= (v.z ? 1u : 0u) << (4 * i + 2);
      bs |= (v.w ? 1u : 0u) << (4 * i + 3);
    }
    bits[w] = bs;
  } else {
    int i = (b - 512) * 1024 + t * 4;  // 48 blocks cover 3*32*512 = 49152 elems
    const float* src = (i < 16384) ? (Wq + i)
                     : (i < 32768) ? (Wk + (i - 16384)) : (Wv + (i - 32768));
    float4 v = *(const float4*)src;
    ushort4v o = { f2bf(v.x), f2bf(v.y), f2bf(v.z), f2bf(v.w) };
    *(ushort4v*)(Wb + i) = o;
  }
}

// ---------------- Merged projections, reg-staged LDS version.
// Block = 64 rows; K=512 in 8 chunks of 64 cols. Per chunk: coalesced
// float4x2 loads (8 consecutive floats of one row per thread; wave = 8 rows
// x 256 contiguous bytes), fp32->bf16 in registers, one ds_write_b128 into a
// byte-XOR-swizzled [64][64] bf16 tile (u ^ ((row&7)<<4)), __syncthreads,
// one conflict-free ds_read_b128 per lane = the full 8-elem A-fragment.
// seg 0=Q (prescaled by log2e/inv_scale), 1=K, 2=V (transposed+kk-permuted).
__global__ __launch_bounds__(256) void proj_kernel(
    const float* __restrict__ Xq, const float* __restrict__ Xk,
    const float* __restrict__ Xv, const unsigned short* __restrict__ Wb,
    const float* __restrict__ bq, const float* __restrict__ bk,
    const float* __restrict__ bv, const float* __restrict__ inv_scale,
    unsigned short* __restrict__ Qb, unsigned short* __restrict__ Kb,
    unsigned short* __restrict__ Vtb) {
  __shared__ unsigned short sb[64 * 64];   // 8 KB, swizzled [row][col] bf16

  int blk  = (int)blockIdx.x;
  int seg  = blk >> 10;
  int tid  = (int)threadIdx.x;
  int wv   = tid >> 6, lane = tid & 63;
  int g = lane >> 4, li = lane & 15;
  int R0 = (blk & 1023) * 64;        // row base within segment (65536 rows)
  int h  = R0 >> 11;
  int s0 = R0 & 2047;

  const float* X    = (seg == 0) ? Xq : (seg == 1) ? Xk : Xv;
  const float* bias = (seg == 0) ? bq : (seg == 1) ? bk : bv;
  const unsigned short* W = Wb + seg * (Dd * Ee);
  const float* xb = X + (size_t)R0 * Ee;

  int r0w = tid >> 3;   // pass-0 write row (0..31); pass 1 adds 32
  int oct = tid & 7;    // 8-float block within the 64-col chunk
  int rrow = wv * 16 + li;                       // this lane's A-frag row
  int rsw  = (li & 7) << 3;                      // read swizzle (ushort units)

  f32x4 acc0 = {0.f, 0.f, 0.f, 0.f};
  f32x4 acc1 = {0.f, 0.f, 0.f, 0.f};

  for (int c = 0; c < 8; ++c) {
    // W fragments for this chunk (bf16, L2/L3-hot)
    const unsigned short* wl = W + (size_t)li * Ee + c * 64 + g * 8;
    ushort8 w00 = *(const ushort8*)(wl);             // ks=0, d=li
    ushort8 w01 = *(const ushort8*)(wl + 16 * Ee);   // ks=0, d=li+16
    ushort8 w10 = *(const ushort8*)(wl + 32);        // ks=1, d=li
    ushort8 w11 = *(const ushort8*)(wl + 16 * Ee + 32);

    // stage chunk: 2 passes x (8 floats -> bf16x8 -> swizzled ds_write_b128)
    #pragma unroll
    for (int p = 0; p < 2; ++p) {
      int r = r0w + 32 * p;
      const float* src = xb + (size_t)r * Ee + c * 64 + oct * 8;
      float4 a = *(const float4*)src;
      float4 b = *(const float4*)(src + 4);
      bf16x8 u;
      u[0] = (__bf16)a.x; u[1] = (__bf16)a.y; u[2] = (__bf16)a.z; u[3] = (__bf16)a.w;
      u[4] = (__bf16)b.x; u[5] = (__bf16)b.y; u[6] = (__bf16)b.z; u[7] = (__bf16)b.w;
      *(ushort8*)&sb[r * 64 + ((oct * 8) ^ ((r & 7) << 3))] =
          __builtin_bit_cast(ushort8, u);
    }
    __syncthreads();

    // A-fragments: one ds_read_b128 per k-half, conflict-free via swizzle
    bf16x8 a0 = __builtin_bit_cast(bf16x8,
        *(const ushort8*)&sb[rrow * 64 + ((g * 8) ^ rsw)]);
    bf16x8 a1 = __builtin_bit_cast(bf16x8,
        *(const ushort8*)&sb[rrow * 64 + ((32 + g * 8) ^ rsw)]);
    acc0 = __builtin_amdgcn_mfma_f32_16x16x32_bf16(
        a0, __builtin_bit_cast(bf16x8, w00), acc0, 0, 0, 0);
    acc1 = __builtin_amdgcn_mfma_f32_16x16x32_bf16(
        a0, __builtin_bit_cast(bf16x8, w01), acc1, 0, 0, 0);
    acc0 = __builtin_amdgcn_mfma_f32_16x16x32_bf16(
        a1, __builtin_bit_cast(bf16x8, w10), acc0, 0, 0, 0);
    acc1 = __builtin_amdgcn_mfma_f32_16x16x32_bf16(
        a1, __builtin_bit_cast(bf16x8, w11), acc1, 0, 0, 0);
    __syncthreads();
  }

  float blo = bias[li], bhi = bias[li + 16];
  float cs = (seg == 0) ? (LOG2E / inv_scale[h]) : 1.0f;
  int sw = s0 + wv * 16;                         // wave's 16-row base (in-head)
  if (seg < 2) {
    unsigned short* ob = ((seg == 0) ? Qb : Kb) +
        (size_t)h * Ss * Dd + (size_t)(sw + 4 * g) * Dd;
    #pragma unroll
    for (int r = 0; r < 4; ++r) {
      ob[r * Dd + li]      = f2bf((acc0[r] + blo) * cs);
      ob[r * Dd + li + 16] = f2bf((acc1[r] + bhi) * cs);
    }
  } else {
    unsigned short* ob = Vtb + (size_t)h * Dd * Ss;
    int s0v = sw + 4 * g;
    int base = (s0v & ~31) + 8 * g + ((s0v & 16) ? 4 : 0);  // PV kk-permuted
    #pragma unroll
    for (int r = 0; r < 4; ++r) {
      ob[(size_t)li * Ss + base + r]        = f2bf(acc0[r] + blo);
      ob[(size_t)(li + 16) * Ss + base + r] = f2bf(acc1[r] + bhi);
    }
  }
}

// ---------------- Flash attention: one BLOCK per (head, 16 q-rows); its 4
// waves each handle 512 keys (split-KV), combined at the end through LDS.
// Q pre-scaled by log2e/inv_scale -> exp2-domain softmax. Swapped QK: lane
// holds scores of ONE q-row (q=q0+li). Defer-max: common path has zero
// cross-lane ops. PV B-frag = single 16-B load from permuted Vt.
__global__ __launch_bounds__(256) void attn_kernel(
    const unsigned short* __restrict__ Qb, const unsigned short* __restrict__ Kb,
    const unsigned short* __restrict__ Vt, const unsigned int* __restrict__ mbits,
    float* __restrict__ out) {
  __shared__ float sO[KV_SPLIT][8][64];
  __shared__ float sM[KV_SPLIT][16];
  __shared__ float sL[KV_SPLIT][16];

  int bid  = (int)blockIdx.x;
  int slot = (bid & 7) * 512 + (bid >> 3);   // XCD-chunked, bijective (4096%8==0)
  int w    = (int)threadIdx.x >> 6;          // kv-split index 0..3
  int lane = (int)threadIdx.x & 63;
  int g = lane >> 4, li = lane & 15;
  int h = slot >> 7, qt = slot & 127;
  int q0 = qt << 4;

  const unsigned short* kb  = Kb + (size_t)h * Ss * Dd;
  const unsigned short* vpb = Vt + (size_t)h * Dd * Ss;
  bf16x8 qf = __builtin_bit_cast(bf16x8,
      *(const ushort8*)(Qb + (size_t)h * Ss * Dd + (size_t)(q0 + li) * Dd + g * 8));
  const unsigned int* mrow = mbits + (size_t)(q0 + li) * (Ss / 32);
  const unsigned short* vlo = vpb + (size_t)li * Ss + 8 * g;         // d = li
  const unsigned short* vhi = vpb + (size_t)(li + 16) * Ss + 8 * g;  // d = li+16

  f32x4 olo = {0.f, 0.f, 0.f, 0.f};
  f32x4 ohi = {0.f, 0.f, 0.f, 0.f};
  float M = -__builtin_inff(), Lp = 0.f;

  int kbeg = w * KV_LEN, kend = kbeg + KV_LEN;
  for (int kt = kbeg; kt < kend; kt += 64) {
    bf16x8 k0 = __builtin_bit_cast(bf16x8, *(const ushort8*)(kb + (size_t)(kt      + li) * Dd + g * 8));
    bf16x8 k1 = __builtin_bit_cast(bf16x8, *(const ushort8*)(kb + (size_t)(kt + 16 + li) * Dd + g * 8));
    bf16x8 k2 = __builtin_bit_cast(bf16x8, *(const ushort8*)(kb + (size_t)(kt + 32 + li) * Dd + g * 8));
    bf16x8 k3 = __builtin_bit_cast(bf16x8, *(const ushort8*)(kb + (size_t)(kt + 48 + li) * Dd + g * 8));
    bf16x8 v0lo = __builtin_bit_cast(bf16x8, *(const ushort8*)(vlo + kt));
    bf16x8 v0hi = __builtin_bit_cast(bf16x8, *(const ushort8*)(vhi + kt));
    bf16x8 v1lo = __builtin_bit_cast(bf16x8, *(const ushort8*)(vlo + kt + 32));
    bf16x8 v1hi = __builtin_bit_cast(bf16x8, *(const ushort8*)(vhi + kt + 32));
    uint2 mw = *(const uint2*)(mrow + (kt >> 5));

    f32x4 z = {0.f, 0.f, 0.f, 0.f};
    f32x4 st0 = __builtin_amdgcn_mfma_f32_16x16x32_bf16(k0, qf, z, 0, 0, 0);
    f32x4 st1 = __builtin_amdgcn_mfma_f32_16x16x32_bf16(k1, qf, z, 0, 0, 0);
    f32x4 st2 = __builtin_amdgcn_mfma_f32_16x16x32_bf16(k2, qf, z, 0, 0, 0);
    f32x4 st3 = __builtin_amdgcn_mfma_f32_16x16x32_bf16(k3, qf, z, 0, 0, 0);

    // ---- half A: keys [kt, kt+32)
    {
      float s[8];
      #pragma unroll
      for (int r = 0; r < 4; ++r) {
        s[r]     = ((mw.x >> (4 * g + r)) & 1u)      ? MNEG : st0[r];
        s[4 + r] = ((mw.x >> (16 + 4 * g + r)) & 1u) ? MNEG : st1[r];
      }
      float pmax = fmaxf(fmaxf(fmaxf(s[0], s[1]), s[2]),
                         fmaxf(fmaxf(s[3], s[4]), fmaxf(fmaxf(s[5], s[6]), s[7])));
      if (!__all(pmax <= M + 8.0f)) {
        float rmax = fmaxf(pmax, __shfl_xor(pmax, 16));
        rmax = fmaxf(rmax, __shfl_xor(rmax, 32));
        float Mn = fmaxf(M, rmax);
        float al = __builtin_amdgcn_exp2f(M - Mn);
        M = Mn; Lp *= al;
        #pragma unroll
        for (int r = 0; r < 4; ++r) {
          float ar = __shfl(al, 4 * g + r);
          olo[r] *= ar; ohi[r] *= ar;
        }
      }
      float p[8];
      #pragma unroll
      for (int j = 0; j < 8; ++j) p[j] = __builtin_amdgcn_exp2f(s[j] - M);
      Lp += ((p[0] + p[1]) + (p[2] + p[3])) + ((p[4] + p[5]) + (p[6] + p[7]));
      bf16x8 af;
      #pragma unroll
      for (int j = 0; j < 8; ++j) af[j] = (__bf16)p[j];
      olo = __builtin_amdgcn_mfma_f32_16x16x32_bf16(af, v0lo, olo, 0, 0, 0);
      ohi = __builtin_amdgcn_mfma_f32_16x16x32_bf16(af, v0hi, ohi, 0, 0, 0);
    }
    // ---- half B: keys [kt+32, kt+64)
    {
      float s[8];
      #pragma unroll
      for (int r = 0; r < 4; ++r) {
        s[r]     = ((mw.y >> (4 * g + r)) & 1u)      ? MNEG : st2[r];
        s[4 + r] = ((mw.y >> (16 + 4 * g + r)) & 1u) ? MNEG : st3[r];
      }
      float pmax = fmaxf(fmaxf(fmaxf(s[0], s[1]), s[2]),
                         fmaxf(fmaxf(s[3], s[4]), fmaxf(fmaxf(s[5], s[6]), s[7])));
      if (!__all(pmax <= M + 8.0f)) {
        float rmax = fmaxf(pmax, __shfl_xor(pmax, 16));
        rmax = fmaxf(rmax, __shfl_xor(rmax, 32));
        float Mn = fmaxf(M, rmax);
        float al = __builtin_amdgcn_exp2f(M - Mn);
        M = Mn; Lp *= al;
        #pragma unroll
        for (int r = 0; r < 4; ++r) {
          float ar = __shfl(al, 4 * g + r);
          olo[r] *= ar; ohi[r] *= ar;
        }
      }
      float p[8];
      #pragma unroll
      for (int j = 0; j < 8; ++j) p[j] = __builtin_amdgcn_exp2f(s[j] - M);
      Lp += ((p[0] + p[1]) + (p[2] + p[3])) + ((p[4] + p[5]) + (p[6] + p[7]));
      bf16x8 af;
      #pragma unroll
      for (int j = 0; j < 8; ++j) af[j] = (__bf16)p[j];
      olo = __builtin_amdgcn_mfma_f32_16x16x32_bf16(af, v1lo, olo, 0, 0, 0);
      ohi = __builtin_amdgcn_mfma_f32_16x16x32_bf16(af, v1hi, ohi, 0, 0, 0);
    }
  }

  // per-row L (sum over the 4 g-replicas), M already row-uniform
  Lp += __shfl_xor(Lp, 16);
  Lp += __shfl_xor(Lp, 32);

  if (lane < 16) { sM[w][lane] = M; sL[w][lane] = Lp; }
  #pragma unroll
  for (int r = 0; r < 4; ++r) {
    sO[w][r][lane]     = olo[r];
    sO[w][4 + r][lane] = ohi[r];
  }
  __syncthreads();

  if (w == 0) {
    float* ob = out + (size_t)h * Ss * Dd + (size_t)q0 * Dd;
    #pragma unroll
    for (int r = 0; r < 4; ++r) {
      int row = 4 * g + r;
      float M0 = sM[0][row], M1 = sM[1][row], M2 = sM[2][row], M3 = sM[3][row];
      float Mg = fmaxf(fmaxf(M0, M1), fmaxf(M2, M3));
      float e0 = __builtin_amdgcn_exp2f(M0 - Mg);
      float e1 = __builtin_amdgcn_exp2f(M1 - Mg);
      float e2 = __builtin_amdgcn_exp2f(M2 - Mg);
      float e3 = __builtin_amdgcn_exp2f(M3 - Mg);
      float den = sL[0][row] * e0 + sL[1][row] * e1 + sL[2][row] * e2 + sL[3][row] * e3;
      float nlo = sO[0][r][lane] * e0 + sO[1][r][lane] * e1 +
                  sO[2][r][lane] * e2 + sO[3][r][lane] * e3;
      float nhi = sO[0][4 + r][lane] * e0 + sO[1][4 + r][lane] * e1 +
                  sO[2][4 + r][lane] * e2 + sO[3][4 + r][lane] * e3;
      float inv = 1.0f / den;
      ob[row * Dd + li]      = nlo * inv;
      ob[row * Dd + li + 16] = nhi * inv;
    }
  }
}

extern "C" void kernel_launch(void* const* d_in, const int* in_sizes, int n_in,
                              void* d_out, int out_size, void* d_ws, size_t ws_size,
                              hipStream_t stream) {
  const float* query = (const float*)d_in[0];
  const float* key   = (const float*)d_in[1];
  const float* value = (const float*)d_in[2];
  const int*   mask  = (const int*)d_in[3];
  const float* Wq = (const float*)d_in[4];
  const float* bq = (const float*)d_in[5];
  const float* Wk = (const float*)d_in[6];
  const float* bk = (const float*)d_in[7];
  const float* Wv = (const float*)d_in[8];
  const float* bv = (const float*)d_in[9];
  const float* inv_scale = (const float*)d_in[10];

  unsigned short* Qb   = (unsigned short*)d_ws;
  unsigned short* Kbuf = Qb + (size_t)Hh * Ss * Dd;
  unsigned short* Vtb  = Kbuf + (size_t)Hh * Ss * Dd;
  unsigned int*   bits = (unsigned int*)(Vtb + (size_t)Hh * Dd * Ss);
  unsigned short* Wb   = (unsigned short*)(bits + (size_t)Ss * Ss / 32);
  float* out = (float*)d_out;

  dim3 blk(256);
  prep_kernel<<<512 + 48, blk, 0, stream>>>(mask, bits, Wq, Wk, Wv, Wb);
  proj_kernel<<<3072, blk, 0, stream>>>(query, key, value, Wb, bq, bk, bv,
                                        inv_scale, Qb, Kbuf, Vtb);
  attn_kernel<<<4096, blk, 0, stream>>>(Qb, Kbuf, Vtb, bits, out);
}

// Round 7
// 197.814 us; speedup vs baseline: 1.6270x; 1.0116x over previous
//
#include <hip/hip_runtime.h>

#define Hh 32
#define Ss 2048
#define Ee 512
#define Dd 32
#define MNEG -1.0e9f
#define LOG2E 1.4426950408889634f
#define KV_SPLIT 4
#define KV_LEN (Ss / KV_SPLIT)   // 512 keys per wave

typedef __attribute__((ext_vector_type(4))) float f32x4;
typedef __attribute__((ext_vector_type(8))) __bf16 bf16x8;
typedef __attribute__((ext_vector_type(8))) unsigned short ushort8;
typedef __attribute__((ext_vector_type(4))) unsigned short ushort4v;

// float -> bf16 round-to-nearest-even, as raw ushort
__device__ inline unsigned short f2bf(float f) {
  union { float f; unsigned u; } x; x.f = f;
  unsigned r = x.u + 0x7fffu + ((x.u >> 16) & 1u);
  return (unsigned short)(r >> 16);
}

// ---------------- Prep: pack mask int32 -> bits, convert Wq|Wk|Wv -> bf16
__global__ __launch_bounds__(256) void prep_kernel(
    const int* __restrict__ mask, unsigned int* __restrict__ bits,
    const float* __restrict__ Wq, const float* __restrict__ Wk,
    const float* __restrict__ Wv, unsigned short* __restrict__ Wb) {
  int b = (int)blockIdx.x, t = (int)threadIdx.x;
  if (b < 512) {
    int w = b * 256 + t;  // word index 0..S*S/32-1
    const int4* p = (const int4*)(mask + (size_t)w * 32);
    unsigned int bs = 0;
    #pragma unroll
    for (int i = 0; i < 8; ++i) {
      int4 v = p[i];
      bs |= (v.x ? 1u : 0u) << (4 * i + 0);
      bs |= (v.y ? 1u : 0u) << (4 * i + 1);
      bs |= (v.z ? 1u : 0u) << (4 * i + 2);
      bs |= (v.w ? 1u : 0u) << (4 * i + 3);
    }
    bits[w] = bs;
  } else {
    int i = (b - 512) * 1024 + t * 4;  // 48 blocks cover 3*32*512 = 49152 elems
    const float* src = (i < 16384) ? (Wq + i)
                     : (i < 32768) ? (Wk + (i - 16384)) : (Wv + (i - 32768));
    float4 v = *(const float4*)src;
    ushort4v o = { f2bf(v.x), f2bf(v.y), f2bf(v.z), f2bf(v.w) };
    *(ushort4v*)(Wb + i) = o;
  }
}

// ---------------- Merged projections, reg-staged + software-pipelined.
// Block = 64 rows; K=512 in 8 chunks of 64 cols. Chunk c+1's global loads
// are issued into REGISTERS before chunk c's LDS write/compute, so the
// memory pipe stays fed across the barrier (reg-destined loads don't force
// a vmcnt drain at __syncthreads; the counted wait lands at next iter's
// convert). LDS double-buffered (2 x 8 KB) -> ONE barrier per chunk:
// per iter: issue(c+1) -> convert+ds_write buf[c&1] -> barrier -> read+MFMA.
// Swizzle/epilogues identical to the round-6 passing kernel.
// seg 0=Q (prescaled by log2e/inv_scale), 1=K, 2=V (transposed+kk-permuted).
__global__ __launch_bounds__(256) void proj_kernel(
    const float* __restrict__ Xq, const float* __restrict__ Xk,
    const float* __restrict__ Xv, const unsigned short* __restrict__ Wb,
    const float* __restrict__ bq, const float* __restrict__ bk,
    const float* __restrict__ bv, const float* __restrict__ inv_scale,
    unsigned short* __restrict__ Qb, unsigned short* __restrict__ Kb,
    unsigned short* __restrict__ Vtb) {
  __shared__ unsigned short sb[2][64 * 64];   // 2 x 8 KB, swizzled bf16 tiles

  int blk  = (int)blockIdx.x;
  int seg  = blk >> 10;
  int tid  = (int)threadIdx.x;
  int wv   = tid >> 6, lane = tid & 63;
  int g = lane >> 4, li = lane & 15;
  int R0 = (blk & 1023) * 64;        // row base within segment (65536 rows)
  int h  = R0 >> 11;
  int s0 = R0 & 2047;

  const float* X    = (seg == 0) ? Xq : (seg == 1) ? Xk : Xv;
  const float* bias = (seg == 0) ? bq : (seg == 1) ? bk : bv;
  const unsigned short* W = Wb + seg * (Dd * Ee);
  const float* xb = X + (size_t)R0 * Ee;

  int r0w = tid >> 3;   // pass-0 write row (0..31); pass 1 adds 32
  int oct = tid & 7;    // 8-float block within the 64-col chunk
  int rrow = wv * 16 + li;                       // this lane's A-frag row
  int rsw  = (li & 7) << 3;                      // read swizzle (ushort units)
  int wofa = r0w * 64 + ((oct * 8) ^ ((r0w & 7) << 3));           // write addr p0
  int wofb = (r0w + 32) * 64 + ((oct * 8) ^ (((r0w + 32) & 7) << 3));

  f32x4 acc0 = {0.f, 0.f, 0.f, 0.f};
  f32x4 acc1 = {0.f, 0.f, 0.f, 0.f};

  // prefetch chunk 0 into registers
  const float* sA = xb + (size_t)r0w * Ee + oct * 8;
  const float* sB = xb + (size_t)(r0w + 32) * Ee + oct * 8;
  float4 ca = *(const float4*)(sA);
  float4 cb = *(const float4*)(sA + 4);
  float4 cc = *(const float4*)(sB);
  float4 cd = *(const float4*)(sB + 4);

  for (int c = 0; c < 8; ++c) {
    // issue chunk c+1 loads (stay in flight through barrier/compute)
    float4 na, nb, nc, nd;
    if (c < 7) {
      na = *(const float4*)(sA + (c + 1) * 64);
      nb = *(const float4*)(sA + (c + 1) * 64 + 4);
      nc = *(const float4*)(sB + (c + 1) * 64);
      nd = *(const float4*)(sB + (c + 1) * 64 + 4);
    }
    // W fragments for this chunk (bf16, L1/L2-hot)
    const unsigned short* wl = W + (size_t)li * Ee + c * 64 + g * 8;
    ushort8 w00 = *(const ushort8*)(wl);             // ks=0, d=li
    ushort8 w01 = *(const ushort8*)(wl + 16 * Ee);   // ks=0, d=li+16
    ushort8 w10 = *(const ushort8*)(wl + 32);        // ks=1, d=li
    ushort8 w11 = *(const ushort8*)(wl + 16 * Ee + 32);

    // convert current chunk -> swizzled ds_write_b128 x2 into buf[c&1]
    {
      bf16x8 u, v;
      u[0] = (__bf16)ca.x; u[1] = (__bf16)ca.y; u[2] = (__bf16)ca.z; u[3] = (__bf16)ca.w;
      u[4] = (__bf16)cb.x; u[5] = (__bf16)cb.y; u[6] = (__bf16)cb.z; u[7] = (__bf16)cb.w;
      v[0] = (__bf16)cc.x; v[1] = (__bf16)cc.y; v[2] = (__bf16)cc.z; v[3] = (__bf16)cc.w;
      v[4] = (__bf16)cd.x; v[5] = (__bf16)cd.y; v[6] = (__bf16)cd.z; v[7] = (__bf16)cd.w;
      *(ushort8*)&sb[c & 1][wofa] = __builtin_bit_cast(ushort8, u);
      *(ushort8*)&sb[c & 1][wofb] = __builtin_bit_cast(ushort8, v);
    }
    __syncthreads();

    // A-fragments: one ds_read_b128 per k-half, conflict-free via swizzle
    bf16x8 a0 = __builtin_bit_cast(bf16x8,
        *(const ushort8*)&sb[c & 1][rrow * 64 + ((g * 8) ^ rsw)]);
    bf16x8 a1 = __builtin_bit_cast(bf16x8,
        *(const ushort8*)&sb[c & 1][rrow * 64 + ((32 + g * 8) ^ rsw)]);
    acc0 = __builtin_amdgcn_mfma_f32_16x16x32_bf16(
        a0, __builtin_bit_cast(bf16x8, w00), acc0, 0, 0, 0);
    acc1 = __builtin_amdgcn_mfma_f32_16x16x32_bf16(
        a0, __builtin_bit_cast(bf16x8, w01), acc1, 0, 0, 0);
    acc0 = __builtin_amdgcn_mfma_f32_16x16x32_bf16(
        a1, __builtin_bit_cast(bf16x8, w10), acc0, 0, 0, 0);
    acc1 = __builtin_amdgcn_mfma_f32_16x16x32_bf16(
        a1, __builtin_bit_cast(bf16x8, w11), acc1, 0, 0, 0);

    ca = na; cb = nb; cc = nc; cd = nd;
  }

  float blo = bias[li], bhi = bias[li + 16];
  float cs = (seg == 0) ? (LOG2E / inv_scale[h]) : 1.0f;
  int sw = s0 + wv * 16;                         // wave's 16-row base (in-head)
  if (seg < 2) {
    unsigned short* ob = ((seg == 0) ? Qb : Kb) +
        (size_t)h * Ss * Dd + (size_t)(sw + 4 * g) * Dd;
    #pragma unroll
    for (int r = 0; r < 4; ++r) {
      ob[r * Dd + li]      = f2bf((acc0[r] + blo) * cs);
      ob[r * Dd + li + 16] = f2bf((acc1[r] + bhi) * cs);
    }
  } else {
    unsigned short* ob = Vtb + (size_t)h * Dd * Ss;
    int s0v = sw + 4 * g;
    int base = (s0v & ~31) + 8 * g + ((s0v & 16) ? 4 : 0);  // PV kk-permuted
    #pragma unroll
    for (int r = 0; r < 4; ++r) {
      ob[(size_t)li * Ss + base + r]        = f2bf(acc0[r] + blo);
      ob[(size_t)(li + 16) * Ss + base + r] = f2bf(acc1[r] + bhi);
    }
  }
}

// ---------------- Flash attention: one BLOCK per (head, 16 q-rows); its 4
// waves each handle 512 keys (split-KV), combined at the end through LDS.
// Q pre-scaled by log2e/inv_scale -> exp2-domain softmax. Swapped QK: lane
// holds scores of ONE q-row (q=q0+li). Defer-max: common path has zero
// cross-lane ops. PV B-frag = single 16-B load from permuted Vt.
__global__ __launch_bounds__(256) void attn_kernel(
    const unsigned short* __restrict__ Qb, const unsigned short* __restrict__ Kb,
    const unsigned short* __restrict__ Vt, const unsigned int* __restrict__ mbits,
    float* __restrict__ out) {
  __shared__ float sO[KV_SPLIT][8][64];
  __shared__ float sM[KV_SPLIT][16];
  __shared__ float sL[KV_SPLIT][16];

  int bid  = (int)blockIdx.x;
  int slot = (bid & 7) * 512 + (bid >> 3);   // XCD-chunked, bijective (4096%8==0)
  int w    = (int)threadIdx.x >> 6;          // kv-split index 0..3
  int lane = (int)threadIdx.x & 63;
  int g = lane >> 4, li = lane & 15;
  int h = slot >> 7, qt = slot & 127;
  int q0 = qt << 4;

  const unsigned short* kb  = Kb + (size_t)h * Ss * Dd;
  const unsigned short* vpb = Vt + (size_t)h * Dd * Ss;
  bf16x8 qf = __builtin_bit_cast(bf16x8,
      *(const ushort8*)(Qb + (size_t)h * Ss * Dd + (size_t)(q0 + li) * Dd + g * 8));
  const unsigned int* mrow = mbits + (size_t)(q0 + li) * (Ss / 32);
  const unsigned short* vlo = vpb + (size_t)li * Ss + 8 * g;         // d = li
  const unsigned short* vhi = vpb + (size_t)(li + 16) * Ss + 8 * g;  // d = li+16

  f32x4 olo = {0.f, 0.f, 0.f, 0.f};
  f32x4 ohi = {0.f, 0.f, 0.f, 0.f};
  float M = -__builtin_inff(), Lp = 0.f;

  int kbeg = w * KV_LEN, kend = kbeg + KV_LEN;
  for (int kt = kbeg; kt < kend; kt += 64) {
    bf16x8 k0 = __builtin_bit_cast(bf16x8, *(const ushort8*)(kb + (size_t)(kt      + li) * Dd + g * 8));
    bf16x8 k1 = __builtin_bit_cast(bf16x8, *(const ushort8*)(kb + (size_t)(kt + 16 + li) * Dd + g * 8));
    bf16x8 k2 = __builtin_bit_cast(bf16x8, *(const ushort8*)(kb + (size_t)(kt + 32 + li) * Dd + g * 8));
    bf16x8 k3 = __builtin_bit_cast(bf16x8, *(const ushort8*)(kb + (size_t)(kt + 48 + li) * Dd + g * 8));
    bf16x8 v0lo = __builtin_bit_cast(bf16x8, *(const ushort8*)(vlo + kt));
    bf16x8 v0hi = __builtin_bit_cast(bf16x8, *(const ushort8*)(vhi + kt));
    bf16x8 v1lo = __builtin_bit_cast(bf16x8, *(const ushort8*)(vlo + kt + 32));
    bf16x8 v1hi = __builtin_bit_cast(bf16x8, *(const ushort8*)(vhi + kt + 32));
    uint2 mw = *(const uint2*)(mrow + (kt >> 5));

    f32x4 z = {0.f, 0.f, 0.f, 0.f};
    f32x4 st0 = __builtin_amdgcn_mfma_f32_16x16x32_bf16(k0, qf, z, 0, 0, 0);
    f32x4 st1 = __builtin_amdgcn_mfma_f32_16x16x32_bf16(k1, qf, z, 0, 0, 0);
    f32x4 st2 = __builtin_amdgcn_mfma_f32_16x16x32_bf16(k2, qf, z, 0, 0, 0);
    f32x4 st3 = __builtin_amdgcn_mfma_f32_16x16x32_bf16(k3, qf, z, 0, 0, 0);

    // ---- half A: keys [kt, kt+32)
    {
      float s[8];
      #pragma unroll
      for (int r = 0; r < 4; ++r) {
        s[r]     = ((mw.x >> (4 * g + r)) & 1u)      ? MNEG : st0[r];
        s[4 + r] = ((mw.x >> (16 + 4 * g + r)) & 1u) ? MNEG : st1[r];
      }
      float pmax = fmaxf(fmaxf(fmaxf(s[0], s[1]), s[2]),
                         fmaxf(fmaxf(s[3], s[4]), fmaxf(fmaxf(s[5], s[6]), s[7])));
      if (!__all(pmax <= M + 8.0f)) {
        float rmax = fmaxf(pmax, __shfl_xor(pmax, 16));
        rmax = fmaxf(rmax, __shfl_xor(rmax, 32));
        float Mn = fmaxf(M, rmax);
        float al = __builtin_amdgcn_exp2f(M - Mn);
        M = Mn; Lp *= al;
        #pragma unroll
        for (int r = 0; r < 4; ++r) {
          float ar = __shfl(al, 4 * g + r);
          olo[r] *= ar; ohi[r] *= ar;
        }
      }
      float p[8];
      #pragma unroll
      for (int j = 0; j < 8; ++j) p[j] = __builtin_amdgcn_exp2f(s[j] - M);
      Lp += ((p[0] + p[1]) + (p[2] + p[3])) + ((p[4] + p[5]) + (p[6] + p[7]));
      bf16x8 af;
      #pragma unroll
      for (int j = 0; j < 8; ++j) af[j] = (__bf16)p[j];
      olo = __builtin_amdgcn_mfma_f32_16x16x32_bf16(af, v0lo, olo, 0, 0, 0);
      ohi = __builtin_amdgcn_mfma_f32_16x16x32_bf16(af, v0hi, ohi, 0, 0, 0);
    }
    // ---- half B: keys [kt+32, kt+64)
    {
      float s[8];
      #pragma unroll
      for (int r = 0; r < 4; ++r) {
        s[r]     = ((mw.y >> (4 * g + r)) & 1u)      ? MNEG : st2[r];
        s[4 + r] = ((mw.y >> (16 + 4 * g + r)) & 1u) ? MNEG : st3[r];
      }
      float pmax = fmaxf(fmaxf(fmaxf(s[0], s[1]), s[2]),
                         fmaxf(fmaxf(s[3], s[4]), fmaxf(fmaxf(s[5], s[6]), s[7])));
      if (!__all(pmax <= M + 8.0f)) {
        float rmax = fmaxf(pmax, __shfl_xor(pmax, 16));
        rmax = fmaxf(rmax, __shfl_xor(rmax, 32));
        float Mn = fmaxf(M, rmax);
        float al = __builtin_amdgcn_exp2f(M - Mn);
        M = Mn; Lp *= al;
        #pragma unroll
        for (int r = 0; r < 4; ++r) {
          float ar = __shfl(al, 4 * g + r);
          olo[r] *= ar; ohi[r] *= ar;
        }
      }
      float p[8];
      #pragma unroll
      for (int j = 0; j < 8; ++j) p[j] = __builtin_amdgcn_exp2f(s[j] - M);
      Lp += ((p[0] + p[1]) + (p[2] + p[3])) + ((p[4] + p[5]) + (p[6] + p[7]));
      bf16x8 af;
      #pragma unroll
      for (int j = 0; j < 8; ++j) af[j] = (__bf16)p[j];
      olo = __builtin_amdgcn_mfma_f32_16x16x32_bf16(af, v1lo, olo, 0, 0, 0);
      ohi = __builtin_amdgcn_mfma_f32_16x16x32_bf16(af, v1hi, ohi, 0, 0, 0);
    }
  }

  // per-row L (sum over the 4 g-replicas), M already row-uniform
  Lp += __shfl_xor(Lp, 16);
  Lp += __shfl_xor(Lp, 32);

  if (lane < 16) { sM[w][lane] = M; sL[w][lane] = Lp; }
  #pragma unroll
  for (int r = 0; r < 4; ++r) {
    sO[w][r][lane]     = olo[r];
    sO[w][4 + r][lane] = ohi[r];
  }
  __syncthreads();

  if (w == 0) {
    float* ob = out + (size_t)h * Ss * Dd + (size_t)q0 * Dd;
    #pragma unroll
    for (int r = 0; r < 4; ++r) {
      int row = 4 * g + r;
      float M0 = sM[0][row], M1 = sM[1][row], M2 = sM[2][row], M3 = sM[3][row];
      float Mg = fmaxf(fmaxf(M0, M1), fmaxf(M2, M3));
      float e0 = __builtin_amdgcn_exp2f(M0 - Mg);
      float e1 = __builtin_amdgcn_exp2f(M1 - Mg);
      float e2 = __builtin_amdgcn_exp2f(M2 - Mg);
      float e3 = __builtin_amdgcn_exp2f(M3 - Mg);
      float den = sL[0][row] * e0 + sL[1][row] * e1 + sL[2][row] * e2 + sL[3][row] * e3;
      float nlo = sO[0][r][lane] * e0 + sO[1][r][lane] * e1 +
                  sO[2][r][lane] * e2 + sO[3][r][lane] * e3;
      float nhi = sO[0][4 + r][lane] * e0 + sO[1][4 + r][lane] * e1 +
                  sO[2][4 + r][lane] * e2 + sO[3][4 + r][lane] * e3;
      float inv = 1.0f / den;
      ob[row * Dd + li]      = nlo * inv;
      ob[row * Dd + li + 16] = nhi * inv;
    }
  }
}

extern "C" void kernel_launch(void* const* d_in, const int* in_sizes, int n_in,
                              void* d_out, int out_size, void* d_ws, size_t ws_size,
                              hipStream_t stream) {
  const float* query = (const float*)d_in[0];
  const float* key   = (const float*)d_in[1];
  const float* value = (const float*)d_in[2];
  const int*   mask  = (const int*)d_in[3];
  const float* Wq = (const float*)d_in[4];
  const float* bq = (const float*)d_in[5];
  const float* Wk = (const float*)d_in[6];
  const float* bk = (const float*)d_in[7];
  const float* Wv = (const float*)d_in[8];
  const float* bv = (const float*)d_in[9];
  const float* inv_scale = (const float*)d_in[10];

  unsigned short* Qb   = (unsigned short*)d_ws;
  unsigned short* Kbuf = Qb + (size_t)Hh * Ss * Dd;
  unsigned short* Vtb  = Kbuf + (size_t)Hh * Ss * Dd;
  unsigned int*   bits = (unsigned int*)(Vtb + (size_t)Hh * Dd * Ss);
  unsigned short* Wb   = (unsigned short*)(bits + (size_t)Ss * Ss / 32);
  float* out = (float*)d_out;

  dim3 blk(256);
  prep_kernel<<<512 + 48, blk, 0, stream>>>(mask, bits, Wq, Wk, Wv, Wb);
  proj_kernel<<<3072, blk, 0, stream>>>(query, key, value, Wb, bq, bk, bv,
                                        inv_scale, Qb, Kbuf, Vtb);
  attn_kernel<<<4096, blk, 0, stream>>>(Qb, Kbuf, Vtb, bits, out);
}